// Round 2
// baseline (5621.289 us; speedup 1.0000x reference)
//
#include <hip/hip_runtime.h>
#include <hip/hip_bf16.h>

#define DOUT 128
#define DIN  256

// ---------------------------------------------------------------------------
// SPMM: S[rows[e]] += vals[e] * h[cols[e]]  over all D*E edges, fp32 atomics.
// S lives in d_out (same size: N x 128 fp32). One wave per edge; lane i
// handles columns {2i, 2i+1} via float2 loads.
// ---------------------------------------------------------------------------
__global__ void spmm_atomic(const int* __restrict__ rows,
                            const int* __restrict__ cols,
                            const float* __restrict__ vals,
                            const float* __restrict__ h,
                            float* __restrict__ S, int nEdges) {
    int wave = (int)((blockIdx.x * blockDim.x + threadIdx.x) >> 6);
    int lane = threadIdx.x & 63;
    if (wave >= nEdges) return;
    int r = rows[wave];
    int c = cols[wave];
    float v = vals[wave];
    const float2* h2 = (const float2*)(h + (size_t)c * DOUT);
    float2 hv = h2[lane];
    float* srow = S + (size_t)r * DOUT;
    atomicAdd(srow + 2 * lane,     v * hv.x);
    atomicAdd(srow + 2 * lane + 1, v * hv.y);
}

// ---------------------------------------------------------------------------
// Fused epilogue, in-place on d_out:
//   out[r,:] = relu(x[r,:] @ W + S[r,:] @ V)   where S[r,:] == out[r,:] (pre)
// One block per row, 128 threads = one per output column, fp32 accumulate.
// Safe in-place: each block reads only its own row before the barrier, writes
// it only after.
// ---------------------------------------------------------------------------
__global__ void fused_out(const float* __restrict__ x,
                          const float* __restrict__ W,
                          const float* __restrict__ V,
                          float* __restrict__ out, int N) {
    __shared__ float xs[DIN];
    __shared__ float ss[DOUT];
    int r = blockIdx.x;
    int col = threadIdx.x;  // 0..127

    const float2* xr = (const float2*)(x + (size_t)r * DIN);
    float2 xv = xr[col];
    xs[2 * col]     = xv.x;
    xs[2 * col + 1] = xv.y;
    ss[col] = out[(size_t)r * DOUT + col];   // S row (accumulated by spmm)
    __syncthreads();

    float acc = 0.f;
#pragma unroll 8
    for (int k = 0; k < DIN; ++k)
        acc += xs[k] * W[k * DOUT + col];
#pragma unroll 8
    for (int k = 0; k < DOUT; ++k)
        acc += ss[k] * V[k * DOUT + col];

    out[(size_t)r * DOUT + col] = fmaxf(acc, 0.f);
}

extern "C" void kernel_launch(void* const* d_in, const int* in_sizes, int n_in,
                              void* d_out, int out_size, void* d_ws, size_t ws_size,
                              hipStream_t stream) {
    const float* x    = (const float*)d_in[0];
    const float* h    = (const float*)d_in[1];
    const int*   rows = (const int*)d_in[2];
    const int*   cols = (const int*)d_in[3];
    const float* vals = (const float*)d_in[4];
    const float* W    = (const float*)d_in[5];
    const float* V    = (const float*)d_in[6];
    // d_in[7] (alpha) is dead: softmax over a size-1 axis == 1.0, so the
    // device-combine weights are all 1 and comb = (sum_d A_d @ h) @ V.

    int nEdges = in_sizes[2];          // D*E = 6.4M
    int N      = in_sizes[1] / DOUT;   // 50000

    float* out = (float*)d_out;

    // S accumulator lives directly in d_out (N*128 fp32 = out_size). Zero it.
    hipMemsetAsync(out, 0, (size_t)N * DOUT * sizeof(float), stream);

    // SPMM: one wave per edge, 4 waves per 256-thread block.
    int nblocks = (nEdges + 3) / 4;
    spmm_atomic<<<nblocks, 256, 0, stream>>>(rows, cols, vals, h, out, nEdges);

    // Fused x@W + S@V + relu, in-place on d_out.
    fused_out<<<N, 128, 0, stream>>>(x, W, V, out, N);
}

// Round 3
// 1542.027 us; speedup vs baseline: 3.6454x; 3.6454x over previous
//
#include <hip/hip_runtime.h>
#include <hip/hip_bf16.h>

#define DOUT 128
#define DIN  256

// ============================ CSR build =====================================

__global__ void hist_rows(const int* __restrict__ rows, int* __restrict__ cnt,
                          int nE) {
    int i = blockIdx.x * blockDim.x + threadIdx.x;
    if (i < nE) atomicAdd(&cnt[rows[i]], 1);
}

// Single-block (1024 threads) chunked Hillis-Steele scan: row_ptr = excl scan.
__global__ void scan_rowptr(const int* __restrict__ cnt, int* __restrict__ row_ptr,
                            int n) {
    __shared__ int buf[1024];
    __shared__ int carry_s;
    int tid = threadIdx.x;
    if (tid == 0) { carry_s = 0; row_ptr[0] = 0; }
    __syncthreads();
    for (int base = 0; base < n; base += 1024) {
        int i = base + tid;
        buf[tid] = (i < n) ? cnt[i] : 0;
        __syncthreads();
        for (int off = 1; off < 1024; off <<= 1) {
            int t = (tid >= off) ? buf[tid - off] : 0;
            __syncthreads();
            buf[tid] += t;
            __syncthreads();
        }
        int carry = carry_s;            // read old carry
        if (i < n) row_ptr[i + 1] = buf[tid] + carry;
        __syncthreads();                // all reads of carry_s done
        if (tid == 1023) carry_s = carry + buf[1023];
        __syncthreads();
    }
}

__global__ void scatter_edges(const int* __restrict__ rows,
                              const int* __restrict__ cols,
                              const float* __restrict__ vals,
                              int* __restrict__ cursor,
                              int* __restrict__ scols,
                              float* __restrict__ svals, int nE) {
    int i = blockIdx.x * blockDim.x + threadIdx.x;
    if (i >= nE) return;
    int r = rows[i];
    int slot = atomicAdd(&cursor[r], 1);
    scols[slot] = cols[i];
    svals[slot] = vals[i];
}

// ============================ SPMM (CSR) ====================================
// One wave per row; lane i owns cols {2i,2i+1}. Edge indices are wave-uniform
// (scalar loads), h gather is the only vector traffic. Single write per elem.
__global__ void spmm_csr(const int* __restrict__ row_ptr,
                         const int* __restrict__ scols,
                         const float* __restrict__ svals,
                         const float* __restrict__ h,
                         float* __restrict__ S, int n) {
    int row = blockIdx.x * 4 + (threadIdx.x >> 6);
    int lane = threadIdx.x & 63;
    if (row >= n) return;
    int beg = row_ptr[row], end = row_ptr[row + 1];
    float2 acc = {0.f, 0.f};
#pragma unroll 4
    for (int e = beg; e < end; ++e) {
        int c = scols[e];
        float v = svals[e];
        float2 hv = ((const float2*)(h + (size_t)c * DOUT))[lane];
        acc.x += v * hv.x;
        acc.y += v * hv.y;
    }
    ((float2*)(S + (size_t)row * DOUT))[lane] = acc;
}

// ==================== fallback: atomic SPMM (round-2 path) ==================
__global__ void spmm_atomic(const int* __restrict__ rows,
                            const int* __restrict__ cols,
                            const float* __restrict__ vals,
                            const float* __restrict__ h,
                            float* __restrict__ S, int nEdges) {
    int wave = (int)((blockIdx.x * blockDim.x + threadIdx.x) >> 6);
    int lane = threadIdx.x & 63;
    if (wave >= nEdges) return;
    int r = rows[wave];
    int c = cols[wave];
    float v = vals[wave];
    float2 hv = ((const float2*)(h + (size_t)c * DOUT))[lane];
    float* srow = S + (size_t)r * DOUT;
    atomicAdd(srow + 2 * lane,     v * hv.x);
    atomicAdd(srow + 2 * lane + 1, v * hv.y);
}

// ============================ fused epilogue ================================
// out[r,:] = relu(x[r,:] @ W + S[r,:] @ V), in place on d_out (S == out row).
__global__ void fused_out(const float* __restrict__ x,
                          const float* __restrict__ W,
                          const float* __restrict__ V,
                          float* __restrict__ out, int N) {
    __shared__ float xs[DIN];
    __shared__ float ss[DOUT];
    int r = blockIdx.x;
    int col = threadIdx.x;  // 0..127

    float2 xv = ((const float2*)(x + (size_t)r * DIN))[col];
    xs[2 * col]     = xv.x;
    xs[2 * col + 1] = xv.y;
    ss[col] = out[(size_t)r * DOUT + col];
    __syncthreads();

    float acc = 0.f;
#pragma unroll 8
    for (int k = 0; k < DIN; ++k)
        acc += xs[k] * W[k * DOUT + col];
#pragma unroll 8
    for (int k = 0; k < DOUT; ++k)
        acc += ss[k] * V[k * DOUT + col];

    out[(size_t)r * DOUT + col] = fmaxf(acc, 0.f);
}

extern "C" void kernel_launch(void* const* d_in, const int* in_sizes, int n_in,
                              void* d_out, int out_size, void* d_ws, size_t ws_size,
                              hipStream_t stream) {
    const float* x    = (const float*)d_in[0];
    const float* h    = (const float*)d_in[1];
    const int*   rows = (const int*)d_in[2];
    const int*   cols = (const int*)d_in[3];
    const float* vals = (const float*)d_in[4];
    const float* W    = (const float*)d_in[5];
    const float* V    = (const float*)d_in[6];
    // d_in[7] (alpha): softmax over size-1 axis == 1 -> dead.

    int nE = in_sizes[2];              // D*E = 6.4M
    int N  = in_sizes[1] / DOUT;       // 50000
    float* out = (float*)d_out;

    // Workspace layout: cnt[N] | row_ptr[N+1] | cursor[N] | scols[nE] | svals[nE]
    size_t need = (size_t)(3 * N + 1) * 4 + (size_t)nE * 8;

    if (ws_size >= need) {
        int*   cnt     = (int*)d_ws;
        int*   row_ptr = cnt + N;
        int*   cursor  = row_ptr + (N + 1);
        int*   scols   = cursor + N;
        float* svals   = (float*)(scols + nE);

        hipMemsetAsync(cnt, 0, (size_t)N * 4, stream);
        hist_rows<<<(nE + 255) / 256, 256, 0, stream>>>(rows, cnt, nE);
        scan_rowptr<<<1, 1024, 0, stream>>>(cnt, row_ptr, N);
        hipMemcpyAsync(cursor, row_ptr, (size_t)N * 4,
                       hipMemcpyDeviceToDevice, stream);
        scatter_edges<<<(nE + 255) / 256, 256, 0, stream>>>(
            rows, cols, vals, cursor, scols, svals, nE);
        // one wave per row, 4 waves/block; every row written exactly once
        spmm_csr<<<(N + 3) / 4, 256, 0, stream>>>(row_ptr, scols, svals, h, out, N);
    } else {
        hipMemsetAsync(out, 0, (size_t)N * DOUT * 4, stream);
        spmm_atomic<<<(nE + 3) / 4, 256, 0, stream>>>(rows, cols, vals, h, out, nE);
    }

    fused_out<<<N, 128, 0, stream>>>(x, W, V, out, N);
}